// Round 9
// baseline (18.544 us; speedup 1.0000x reference)
//
#include <hip/hip_runtime.h>
#include <math.h>

#define NG 512
#define NV 76800
#define FD 32
#define CAP 64
// voxel grid 80x80x12; tiles 10x10x3 -> 8x8x4 = 256 blocks (1 per CU), 320 threads
// R8 = calibration round: real kernel + 3x null kernels to measure per-graph-node
// overhead g. dur = F + k_real + 3*(g + ~0.3us).

__global__ __launch_bounds__(64) void null_kernel(float* __restrict__ ws) {
    // never-taken store (blockIdx.x == 0 always; compiler can't fold the cast trick)
    if ((int)(blockIdx.x + threadIdx.x) < -1) ws[0] = 1.f;
}

__global__ __launch_bounds__(320) void voxelize_kernel(
    const float* __restrict__ means, const float* __restrict__ opac,
    const float* __restrict__ cov, const float* __restrict__ feats,
    float* __restrict__ out)
{
    __shared__ float4 gp[CAP];   // mx,my,mz,r2
    __shared__ float4 gq[CAP];   // i00,i01,i02,i11
    __shared__ float4 gt[CAP];   // i12,i22,op,-
    __shared__ int    s_n[CAP];
    __shared__ int    s_cnt;

    const int tid  = threadIdx.x;
    const int lane = tid & 63;

    const int b   = blockIdx.x;
    const int tiz = b & 3;           // 0..3
    const int tiy = (b >> 2) & 7;    // 0..7
    const int tix = b >> 5;          // 0..7

    // tile voxel-center AABB (world units): 10x10x3 voxels
    const float xlo = (tix * 10 + 0.5f) * 0.5f - 20.f, xhi = xlo + 4.5f;
    const float ylo = (tiy * 10 + 0.5f) * 0.5f - 20.f, yhi = ylo + 4.5f;
    const float zlo = (tiz * 3  + 0.5f) * 0.5f -  2.f, zhi = zlo + 1.0f;

    if (tid == 0) s_cnt = 0;
    __syncthreads();

    // ---- phase 1: gate 512 gaussians (2 rounds over 320 threads), compact survivors
    #pragma unroll
    for (int r = 0; r < 2; ++r) {
        const int n = r * 320 + tid;
        if (n < NG) {
            const float a = cov[n*9+0], bb = cov[n*9+1], c = cov[n*9+2];
            const float d = cov[n*9+4], e  = cov[n*9+5], f = cov[n*9+8];
            const float sx = sqrtf(a), sy = sqrtf(d), sz = sqrtf(f);
            const float mx = means[n*3+0], my = means[n*3+1], mz = means[n*3+2];
            const float op = opac[n];
            const bool keep =
                (mx + 3.f*sx > -20.f) && (my + 3.f*sy > -20.f) && (mz + 3.f*sz > -2.f) &&
                (mx - 3.f*sx <  20.f) && (my - 3.f*sy <  20.f) && (mz - 3.f*sz <  4.4f) &&
                (op > 1e-4f);
            const float smax = fmaxf(sx, fmaxf(sy, sz));
            const float r2 = 9.f * smax * smax;
            const float cx = fminf(fmaxf(mx, xlo), xhi) - mx;
            const float cy = fminf(fmaxf(my, ylo), yhi) - my;
            const float cz = fminf(fmaxf(mz, zlo), zhi) - mz;
            const float d2t = cx*cx + cy*cy + cz*cz;
            const bool pred = keep && (d2t < r2);

            const unsigned long long m = __ballot(pred);
            int wofs = 0;
            if (lane == 0) wofs = atomicAdd(&s_cnt, (int)__popcll(m));
            wofs = __shfl(wofs, 0);
            const int pos = wofs + (int)__popcll(m & ((1ull << lane) - 1ull));
            if (pred && pos < CAP) {
                const float det = a*(d*f - e*e) - bb*(bb*f - c*e) + c*(bb*e - c*d);
                const float id = 1.f / det;
                gp[pos] = make_float4(mx, my, mz, r2);
                gq[pos] = make_float4((d*f - e*e) * id,   // i00
                                      (c*e - bb*f) * id,  // i01
                                      (bb*e - c*d) * id,  // i02
                                      (a*f - c*c) * id);  // i11
                gt[pos] = make_float4((bb*c - a*e) * id,  // i12
                                      (a*d - bb*bb) * id, // i22
                                      op, 0.f);
                s_n[pos] = n;
            }
        }
    }
    __syncthreads();
    const int ks = (s_cnt < CAP) ? s_cnt : CAP;

    // ---- phase 2: voxel threads (u < 300); no barriers below
    const int u = tid;
    if (u < 300) {
        const int lz = u % 3;
        const int ly = (u / 3) % 10;
        const int lx = u / 30;
        const int ix = tix * 10 + lx;
        const int iy = tiy * 10 + ly;
        const int iz = tiz * 3  + lz;
        const float x = (ix + 0.5f) * 0.5f - 20.f;
        const float y = (iy + 0.5f) * 0.5f - 20.f;
        const float z = (iz + 0.5f) * 0.5f -  2.f;

        // pass A: branchless gate walk -> per-lane hit bitmask (broadcast LDS reads)
        unsigned long long hm = 0ull;
        for (int i = 0; i < ks; ++i) {
            const float4 p = gp[i];
            const float dx = p.x - x, dy = p.y - y, dz = p.z - z;
            const float d2 = dx*dx + dy*dy + dz*dz;
            hm |= (d2 < p.w) ? (1ull << i) : 0ull;
        }

        // pass B: per-lane walk of set bits only (~1-3 hits)
        float dens = 0.f;
        float4 acc[8];
        #pragma unroll
        for (int j = 0; j < 8; ++j) acc[j] = make_float4(0.f, 0.f, 0.f, 0.f);

        while (hm) {
            const int i = (int)__builtin_ctzll(hm);
            hm &= hm - 1ull;
            const float4 p = gp[i];
            const float4 q = gq[i];
            const float4 t = gt[i];
            const float dx = p.x - x, dy = p.y - y, dz = p.z - z;
            const float maha = q.x*dx*dx + q.w*dy*dy + t.y*dz*dz
                             + 2.f*(q.y*dx*dy + q.z*dx*dz + t.x*dy*dz);
            const float w = t.z * __expf(-0.5f * maha);
            dens += w;
            const float4* fp = (const float4*)(feats + (size_t)s_n[i] * FD);
            #pragma unroll
            for (int j = 0; j < 8; ++j) {
                const float4 f4 = fp[j];
                acc[j].x += w * f4.x; acc[j].y += w * f4.y;
                acc[j].z += w * f4.z; acc[j].w += w * f4.w;
            }
        }

        const int v = (ix * 80 + iy) * 12 + iz;
        out[v] = dens;
        const float inv = 1.f / fmaxf(dens, 1e-6f);
        float4* fo = (float4*)(out + NV + (size_t)v * FD);
        #pragma unroll
        for (int j = 0; j < 8; ++j) {
            float4 rr;
            rr.x = acc[j].x * inv; rr.y = acc[j].y * inv;
            rr.z = acc[j].z * inv; rr.w = acc[j].w * inv;
            fo[j] = rr;
        }
    }
}

extern "C" void kernel_launch(void* const* d_in, const int* in_sizes, int n_in,
                              void* d_out, int out_size, void* d_ws, size_t ws_size,
                              hipStream_t stream) {
    const float* means = (const float*)d_in[0];
    const float* opac  = (const float*)d_in[1];
    const float* cov   = (const float*)d_in[2];
    const float* feats = (const float*)d_in[3];
    float* out = (float*)d_out;
    float* ws  = (float*)d_ws;

    voxelize_kernel<<<256, 320, 0, stream>>>(means, opac, cov, feats, out);
    null_kernel<<<1, 64, 0, stream>>>(ws);
    null_kernel<<<1, 64, 0, stream>>>(ws);
    null_kernel<<<1, 64, 0, stream>>>(ws);
}

// Round 10
// 15.885 us; speedup vs baseline: 1.1674x; 1.1674x over previous
//
#include <hip/hip_runtime.h>
#include <math.h>

#define NG 512
#define NV 76800
#define FD 32
#define CAP 128
// voxel grid 80x80x12; tiles 8x8x12 (full z) -> 10x10 = 100 blocks x 768 threads.
// Epilogue: per-lx-slice LDS transpose -> contiguous 12KB coalesced feature writes.

__global__ __launch_bounds__(768) void voxelize_kernel(
    const float* __restrict__ means, const float* __restrict__ opac,
    const float* __restrict__ cov, const float* __restrict__ feats,
    float* __restrict__ out)
{
    __shared__ float4 gp[CAP];          // mx,my,mz,r2
    __shared__ float4 gq[CAP];          // i00,i01,i02,i11
    __shared__ float4 gt[CAP];          // i12,i22,op,-
    __shared__ int    s_n[CAP];
    __shared__ int    s_cnt;
    __shared__ float4 ldsF[2][96][9];   // staged feature rows (pad to 9 float4)
    __shared__ float  ldsD[2][96];      // staged density

    const int tid  = threadIdx.x;
    const int lane = tid & 63;

    const int b   = blockIdx.x;
    const int tiy = b % 10;
    const int tix = b / 10;

    // tile voxel-center AABB (world units): 8x8x12 voxels
    const float xlo = (tix * 8 + 0.5f) * 0.5f - 20.f, xhi = xlo + 3.5f;
    const float ylo = (tiy * 8 + 0.5f) * 0.5f - 20.f, yhi = ylo + 3.5f;
    const float zlo = 0.5f * 0.5f - 2.f,               zhi = zlo + 5.5f;

    if (tid == 0) s_cnt = 0;
    __syncthreads();

    // ---- phase 1: gate 512 gaussians (threads 0..511), compact survivors
    if (tid < NG) {
        const int n = tid;
        const float a = cov[n*9+0], bb = cov[n*9+1], c = cov[n*9+2];
        const float d = cov[n*9+4], e  = cov[n*9+5], f = cov[n*9+8];
        const float sx = sqrtf(a), sy = sqrtf(d), sz = sqrtf(f);
        const float mx = means[n*3+0], my = means[n*3+1], mz = means[n*3+2];
        const float op = opac[n];
        const bool keep =
            (mx + 3.f*sx > -20.f) && (my + 3.f*sy > -20.f) && (mz + 3.f*sz > -2.f) &&
            (mx - 3.f*sx <  20.f) && (my - 3.f*sy <  20.f) && (mz - 3.f*sz <  4.4f) &&
            (op > 1e-4f);
        const float smax = fmaxf(sx, fmaxf(sy, sz));
        const float r2 = 9.f * smax * smax;
        const float cx = fminf(fmaxf(mx, xlo), xhi) - mx;
        const float cy = fminf(fmaxf(my, ylo), yhi) - my;
        const float cz = fminf(fmaxf(mz, zlo), zhi) - mz;
        const float d2t = cx*cx + cy*cy + cz*cz;
        const bool pred = keep && (d2t < r2);

        const unsigned long long m = __ballot(pred);
        int wofs = 0;
        if (lane == 0) wofs = atomicAdd(&s_cnt, (int)__popcll(m));
        wofs = __shfl(wofs, 0);
        const int pos = wofs + (int)__popcll(m & ((1ull << lane) - 1ull));
        if (pred && pos < CAP) {
            const float det = a*(d*f - e*e) - bb*(bb*f - c*e) + c*(bb*e - c*d);
            const float id = 1.f / det;
            gp[pos] = make_float4(mx, my, mz, r2);
            gq[pos] = make_float4((d*f - e*e) * id,   // i00
                                  (c*e - bb*f) * id,  // i01
                                  (bb*e - c*d) * id,  // i02
                                  (a*f - c*c) * id);  // i11
            gt[pos] = make_float4((bb*c - a*e) * id,  // i12
                                  (a*d - bb*bb) * id, // i22
                                  op, 0.f);
            s_n[pos] = n;
        }
    }
    __syncthreads();
    const int ks = (s_cnt < CAP) ? s_cnt : CAP;
    const int k0 = (ks < 64) ? ks : 64;

    // ---- phase 2: bitmask gate walk + sparse payload
    const int lx  = tid / 96;          // x-slice 0..7
    const int rem = tid - lx * 96;     // (ly,lz) 0..95
    const int ly  = rem / 12;
    const int lz  = rem - ly * 12;
    const int ix = tix * 8 + lx;
    const int iy = tiy * 8 + ly;
    const int iz = lz;
    const float x = (ix + 0.5f) * 0.5f - 20.f;
    const float y = (iy + 0.5f) * 0.5f - 20.f;
    const float z = (iz + 0.5f) * 0.5f -  2.f;

    // pass A: branchless gate walk -> 128-bit per-lane hit mask (broadcast LDS reads)
    unsigned long long hm0 = 0ull, hm1 = 0ull;
    for (int i = 0; i < k0; ++i) {
        const float4 p = gp[i];
        const float dx = p.x - x, dy = p.y - y, dz = p.z - z;
        const float d2 = dx*dx + dy*dy + dz*dz;
        hm0 |= (d2 < p.w) ? (1ull << i) : 0ull;
    }
    for (int i = 64; i < ks; ++i) {
        const float4 p = gp[i];
        const float dx = p.x - x, dy = p.y - y, dz = p.z - z;
        const float d2 = dx*dx + dy*dy + dz*dz;
        hm1 |= (d2 < p.w) ? (1ull << (i - 64)) : 0ull;
    }

    // pass B: walk set bits only (~1-3 hits/lane)
    float dens = 0.f;
    float4 acc[8];
    #pragma unroll
    for (int j = 0; j < 8; ++j) acc[j] = make_float4(0.f, 0.f, 0.f, 0.f);

    #pragma unroll
    for (int wsel = 0; wsel < 2; ++wsel) {
        unsigned long long hm = wsel ? hm1 : hm0;
        const int ofs = wsel ? 64 : 0;
        while (hm) {
            const int i = (int)__builtin_ctzll(hm) + ofs;
            hm &= hm - 1ull;
            const float4 p = gp[i];
            const float4 q = gq[i];
            const float4 t = gt[i];
            const float dx = p.x - x, dy = p.y - y, dz = p.z - z;
            const float maha = q.x*dx*dx + q.w*dy*dy + t.y*dz*dz
                             + 2.f*(q.y*dx*dy + q.z*dx*dz + t.x*dy*dz);
            const float w = t.z * __expf(-0.5f * maha);
            dens += w;
            const float4* fp = (const float4*)(feats + (size_t)s_n[i] * FD);
            #pragma unroll
            for (int j = 0; j < 8; ++j) {
                const float4 f4 = fp[j];
                acc[j].x += w * f4.x; acc[j].y += w * f4.y;
                acc[j].z += w * f4.z; acc[j].w += w * f4.w;
            }
        }
    }

    // normalize in-register
    const float inv = 1.f / fmaxf(dens, 1e-6f);
    #pragma unroll
    for (int j = 0; j < 8; ++j) {
        acc[j].x *= inv; acc[j].y *= inv; acc[j].z *= inv; acc[j].w *= inv;
    }

    // ---- epilogue: per-lx-slice LDS transpose -> contiguous coalesced writes
    // slice s output: dens run of 96 floats at Dbase(s); feats run of 3072 floats
    // (= 768 float4) at NV + Dbase(s)*32. Double-buffered LDS, 8 barriers.
    for (int s = 0; s < 8; ++s) {
        const int bi = s & 1;
        if (lx == s) {
            ldsD[bi][rem] = dens;
            #pragma unroll
            for (int j = 0; j < 8; ++j) ldsF[bi][rem][j] = acc[j];
        }
        __syncthreads();
        const int Dbase = ((tix * 8 + s) * 80 + tiy * 8) * 12;
        if (tid < 96) out[Dbase + tid] = ldsD[bi][tid];
        const int vox = tid >> 3, j = tid & 7;
        ((float4*)(out + NV + (size_t)Dbase * FD))[tid] = ldsF[bi][vox][j];
    }
}

extern "C" void kernel_launch(void* const* d_in, const int* in_sizes, int n_in,
                              void* d_out, int out_size, void* d_ws, size_t ws_size,
                              hipStream_t stream) {
    const float* means = (const float*)d_in[0];
    const float* opac  = (const float*)d_in[1];
    const float* cov   = (const float*)d_in[2];
    const float* feats = (const float*)d_in[3];
    float* out = (float*)d_out;
    voxelize_kernel<<<100, 768, 0, stream>>>(means, opac, cov, feats, out);
}